// Round 1
// 220.095 us; speedup vs baseline: 1.0028x; 1.0028x over previous
//
#include <hip/hip_runtime.h>

#define N_NODES 100000
#define N_EDGES 20000
#define NNZ_C   600000
#define D 128

typedef short bf16x8 __attribute__((ext_vector_type(8)));
typedef float f32x4  __attribute__((ext_vector_type(4)));

__device__ __forceinline__ unsigned short f2bf(float f) {
    unsigned int u = __float_as_uint(f);
    u = (u + 0x7fffu + ((u >> 16) & 1u)) >> 16;   // RNE
    return (unsigned short)u;
}
__device__ __forceinline__ float bf2f(unsigned short h) {
    return __uint_as_float((unsigned int)h << 16);
}
// pack two fp32 -> two bf16 (truncation) in one v_perm_b32
__device__ __forceinline__ unsigned int pk_trunc(float lo, float hi) {
    return __builtin_amdgcn_perm(__float_as_uint(hi), __float_as_uint(lo),
                                 0x07060302);
}

// ---------------------------------------------------------------------------
// binning constants: fine buckets, 32 ids per bucket -> aggregation kernels
// counting-sort their own bucket in LDS (no global CSR pass needed).
// ---------------------------------------------------------------------------
#define CHA 8192
#define NBLK_A 74             // ceil(600000/8192)
#define EBW 32                // edges per bucket
#define NBE 625               // 20000/32 (exact)
#define ECAP 1536             // mean 960, sigma ~31 -> +18 sigma
#define NBW 32                // nodes per bucket
#define NBN 3125              // 100000/32 (exact)
#define NCAP 512              // mean 192, sigma ~14 -> +23 sigma

// ---------------------------------------------------------------------------
// Pass A: bucket COO by id-range for BOTH sides in one read. Trailing blocks
// do the W transposes (fp32 -> bf16, [f][k]).
// ---------------------------------------------------------------------------
__global__ __launch_bounds__(256) void bin_pass(
    const int* __restrict__ nidx, const int* __restrict__ eidx,
    const float* __restrict__ cW, const float* __restrict__ rW,
    unsigned short* __restrict__ wtc, unsigned short* __restrict__ wtr,
    int* __restrict__ bucket_e, int* __restrict__ bucket_n,
    int* __restrict__ gcur_e, int* __restrict__ gcur_n) {
    const int bid = blockIdx.x;
    if (bid >= NBLK_A) {   // W transpose: 8 blocks x 4096 elements
        const int t0 = (bid - NBLK_A) * 4096;
        for (int i = threadIdx.x; i < 4096; i += 256) {
            const int t = t0 + i;
            const int m = t >> 14, idx = t & 16383;
            const int f = idx & 127, k = idx >> 7;
            const float* src = m ? rW : cW;
            unsigned short* dst = m ? wtr : wtc;
            dst[f * D + k] = f2bf(src[k * D + f]);
        }
        return;
    }
    const int jbeg = bid * CHA;
    const int jend = (jbeg + CHA < NNZ_C) ? jbeg + CHA : NNZ_C;
    __shared__ int cnt_e[NBE], base_e[NBE];
    __shared__ int cnt_n[NBN], base_n[NBN];
    for (int i = threadIdx.x; i < NBE; i += 256) cnt_e[i] = 0;
    for (int i = threadIdx.x; i < NBN; i += 256) cnt_n[i] = 0;
    __syncthreads();
    for (int j = jbeg + threadIdx.x; j < jend; j += 256) {
        atomicAdd(&cnt_e[eidx[j] >> 5], 1);
        atomicAdd(&cnt_n[nidx[j] >> 5], 1);
    }
    __syncthreads();
    for (int i = threadIdx.x; i < NBE; i += 256) {
        const int c = cnt_e[i];
        base_e[i] = c ? atomicAdd(&gcur_e[i], c) : 0;
        cnt_e[i] = 0;
    }
    for (int i = threadIdx.x; i < NBN; i += 256) {
        const int c = cnt_n[i];
        base_n[i] = c ? atomicAdd(&gcur_n[i], c) : 0;
        cnt_n[i] = 0;
    }
    __syncthreads();
    for (int j = jbeg + threadIdx.x; j < jend; j += 256) {
        const int e = eidx[j], n = nidx[j];
        {
            const int b = e >> 5;
            const int pos = base_e[b] + atomicAdd(&cnt_e[b], 1);
            if (pos < ECAP) bucket_e[b * ECAP + pos] = ((e & 31) << 17) | n;
        }
        {
            const int b = n >> 5;
            const int pos = base_n[b] + atomicAdd(&cnt_n[b], 1);
            if (pos < NCAP) bucket_n[b * NCAP + pos] = ((n & 31) << 15) | e;
        }
    }
}

// ---------------------------------------------------------------------------
// MFMA dual GEMM: weights in registers, x double-buffered in LDS (bf16).
// yb = bf16(x @ cW), resb = bf16(x @ rW)  (bias deferred to node_aggregate)
// ---------------------------------------------------------------------------
#define GT 64
#define XPAD 136
#define NTILES ((N_NODES + GT - 1) / GT)   // 1563

__device__ __forceinline__ void stage_tile(unsigned short* __restrict__ buf,
                                           const float* __restrict__ x,
                                           int tile, int r0, int qp) {
    int n = tile * GT + r0;
    if (n >= N_NODES) n = N_NODES - 1;
    const float* xr = x + (size_t)n * D + qp * 16;
    unsigned short* dst = buf + r0 * XPAD + qp * 16;
#pragma unroll
    for (int u = 0; u < 2; ++u) {
        const float4 a = *(const float4*)(xr + u * 8);
        const float4 c = *(const float4*)(xr + u * 8 + 4);
        uint4 v;
        v.x = pk_trunc(a.x, a.y);
        v.y = pk_trunc(a.z, a.w);
        v.z = pk_trunc(c.x, c.y);
        v.w = pk_trunc(c.z, c.w);
        *(uint4*)(dst + u * 8) = v;
    }
}

__device__ __forceinline__ void compute_tile(
    const unsigned short* __restrict__ buf, const bf16x8 (&A)[2][4],
    int tile, int mat, int fh, int quad, int l16,
    unsigned short* __restrict__ yb, unsigned short* __restrict__ resb) {
    f32x4 acc[4][2] = {};
#pragma unroll
    for (int g = 0; g < 4; ++g)
#pragma unroll
        for (int kc = 0; kc < 4; ++kc) {
            const bf16x8 B = *(const bf16x8*)(buf + (g * 16 + l16) * XPAD +
                                              kc * 32 + quad * 8);
            acc[g][0] = __builtin_amdgcn_mfma_f32_16x16x32_bf16(A[0][kc], B, acc[g][0], 0, 0, 0);
            acc[g][1] = __builtin_amdgcn_mfma_f32_16x16x32_bf16(A[1][kc], B, acc[g][1], 0, 0, 0);
        }
    const int nbase = tile * GT;
    unsigned short* dst = mat ? resb : yb;
#pragma unroll
    for (int g = 0; g < 4; ++g) {
        const int n = nbase + g * 16 + l16;
        if (n >= N_NODES) continue;
#pragma unroll
        for (int ft = 0; ft < 2; ++ft) {
            const int f0 = fh + ft * 16 + quad * 4;
            uint2 v;
            v.x = pk_trunc(acc[g][ft][0], acc[g][ft][1]);
            v.y = pk_trunc(acc[g][ft][2], acc[g][ft][3]);
            *(uint2*)(dst + (size_t)n * D + f0) = v;
        }
    }
}

__global__ __launch_bounds__(512) void mfma_gemm(
    const float* __restrict__ x, const unsigned short* __restrict__ wtc,
    const unsigned short* __restrict__ wtr,
    unsigned short* __restrict__ yb, unsigned short* __restrict__ resb) {
    __shared__ unsigned short xs[2][GT * XPAD];

    const int w    = threadIdx.x >> 6;
    const int lane = threadIdx.x & 63;
    const int quad = lane >> 4;
    const int l16  = lane & 15;
    const int mat  = w & 1;
    const int fh   = (w >> 1) * 32;

    const unsigned short* wsrc = mat ? wtr : wtc;
    bf16x8 A[2][4];
#pragma unroll
    for (int ft = 0; ft < 2; ++ft)
#pragma unroll
        for (int kc = 0; kc < 4; ++kc)
            A[ft][kc] = *(const bf16x8*)(wsrc + (fh + ft * 16 + l16) * D +
                                         kc * 32 + quad * 8);

    const int r0 = threadIdx.x >> 3;
    const int qp = threadIdx.x & 7;
    const int t0 = blockIdx.x * 2;

    stage_tile(xs[0], x, t0, r0, qp);
    __syncthreads();
    stage_tile(xs[1], x, t0 + 1, r0, qp);
    compute_tile(xs[0], A, t0, mat, fh, quad, l16, yb, resb);
    __syncthreads();
    compute_tile(xs[1], A, t0 + 1, mat, fh, quad, l16, yb, resb);
}

// ---------------------------------------------------------------------------
// edge aggregation (fused local sort): block = 32-edge bucket. Counting-sort
// bucket entries by local edge id in LDS, then the proven 16-lane-per-edge
// gather loop. Replaces the global CSR scatter pass entirely.
// ---------------------------------------------------------------------------
__global__ __launch_bounds__(256) void edge_aggregate(
    const int* __restrict__ bucket_e, const int* __restrict__ gcur_e,
    const unsigned short* __restrict__ yb, unsigned short* __restrict__ efb) {
    __shared__ int raw[ECAP];
    __shared__ int srt[ECAP];
    __shared__ int cnt[EBW + 1];
    __shared__ int cur[EBW];
    const int tid = threadIdx.x;
    const int b = blockIdx.x;
    int W = gcur_e[b];
    if (W > ECAP) W = ECAP;
    if (tid < EBW + 1) cnt[tid] = 0;
    __syncthreads();
    const int* src = bucket_e + b * ECAP;
    for (int i = tid; i < W; i += 256) {
        const int p = src[i];
        raw[i] = p;
        atomicAdd(&cnt[p >> 17], 1);
    }
    __syncthreads();
    if (tid < EBW) {        // wave-0 exclusive scan over 32 bins
        const int c = cnt[tid];
        int v = c;
#pragma unroll
        for (int off = 1; off < EBW; off <<= 1) {
            const int t = __shfl_up(v, off);
            if (tid >= off) v += t;
        }
        cnt[tid] = v - c;
        cur[tid] = v - c;
        if (tid == EBW - 1) cnt[EBW] = v;
    }
    __syncthreads();
    for (int i = tid; i < W; i += 256) {
        const int p = raw[i];
        const int pos = atomicAdd(&cur[p >> 17], 1);
        srt[pos] = p & 0x1FFFF;
    }
    __syncthreads();

    const int g = tid >> 4;       // 16 groups, 2 edges each
    const int l = tid & 15;       // lane = 8 cols (16B)
#pragma unroll
    for (int u = 0; u < 2; ++u) {
        const int el = g * 2 + u;
        const int beg = cnt[el], end = cnt[el + 1];
        float acc[8] = {};
        int j = beg;
        for (; j + 4 <= end; j += 4) {
            const int n0 = srt[j], n1 = srt[j + 1];
            const int n2 = srt[j + 2], n3 = srt[j + 3];
            const bf16x8 p0 = *(const bf16x8*)(yb + (size_t)n0 * D + l * 8);
            const bf16x8 p1 = *(const bf16x8*)(yb + (size_t)n1 * D + l * 8);
            const bf16x8 p2 = *(const bf16x8*)(yb + (size_t)n2 * D + l * 8);
            const bf16x8 p3 = *(const bf16x8*)(yb + (size_t)n3 * D + l * 8);
#pragma unroll
            for (int i = 0; i < 8; ++i)
                acc[i] += (bf2f((unsigned short)p0[i]) + bf2f((unsigned short)p1[i]))
                        + (bf2f((unsigned short)p2[i]) + bf2f((unsigned short)p3[i]));
        }
        for (; j < end; ++j) {
            const bf16x8 p = *(const bf16x8*)(yb + (size_t)srt[j] * D + l * 8);
#pragma unroll
            for (int i = 0; i < 8; ++i) acc[i] += bf2f((unsigned short)p[i]);
        }
        const int deg = end - beg;
        const float inv = deg ? 1.f / (float)deg : 0.f;
        bf16x8 o;
#pragma unroll
        for (int i = 0; i < 8; ++i) o[i] = (short)f2bf(acc[i] * inv);
        *(bf16x8*)(efb + (size_t)(b * EBW + el) * D + l * 8) = o;
    }
}

// ---------------------------------------------------------------------------
// node aggregation (fused local sort): block = 32-node bucket. Sort by local
// node id, gather efb rows, epilogue out = resb + acc*inv + rb + cb.
// Sole writer of out (fp32).
// ---------------------------------------------------------------------------
__global__ __launch_bounds__(256) void node_aggregate(
    const int* __restrict__ bucket_n, const int* __restrict__ gcur_n,
    const unsigned short* __restrict__ efb, const unsigned short* __restrict__ resb,
    const float* __restrict__ rb, const float* __restrict__ cb,
    float* __restrict__ out) {
    __shared__ int raw[NCAP];
    __shared__ int srt[NCAP];
    __shared__ int cnt[NBW + 1];
    __shared__ int cur[NBW];
    const int tid = threadIdx.x;
    const int b = blockIdx.x;
    int W = gcur_n[b];
    if (W > NCAP) W = NCAP;
    if (tid < NBW + 1) cnt[tid] = 0;
    __syncthreads();
    const int* src = bucket_n + b * NCAP;
    for (int i = tid; i < W; i += 256) {
        const int p = src[i];
        raw[i] = p;
        atomicAdd(&cnt[p >> 15], 1);
    }
    __syncthreads();
    if (tid < NBW) {
        const int c = cnt[tid];
        int v = c;
#pragma unroll
        for (int off = 1; off < NBW; off <<= 1) {
            const int t = __shfl_up(v, off);
            if (tid >= off) v += t;
        }
        cnt[tid] = v - c;
        cur[tid] = v - c;
        if (tid == NBW - 1) cnt[NBW] = v;
    }
    __syncthreads();
    for (int i = tid; i < W; i += 256) {
        const int p = raw[i];
        const int pos = atomicAdd(&cur[p >> 15], 1);
        srt[pos] = p & 0x7FFF;
    }
    __syncthreads();

    const int g = tid >> 4;       // 16 groups, 2 nodes each
    const int l = tid & 15;
#pragma unroll
    for (int u = 0; u < 2; ++u) {
        const int nl = g * 2 + u;
        const int n = b * NBW + nl;
        const int beg = cnt[nl], end = cnt[nl + 1];
        float acc[8] = {};
        int j = beg;
        for (; j + 2 <= end; j += 2) {
            const int e0 = srt[j], e1 = srt[j + 1];
            const bf16x8 p0 = *(const bf16x8*)(efb + (size_t)e0 * D + l * 8);
            const bf16x8 p1 = *(const bf16x8*)(efb + (size_t)e1 * D + l * 8);
#pragma unroll
            for (int i = 0; i < 8; ++i)
                acc[i] += bf2f((unsigned short)p0[i]) + bf2f((unsigned short)p1[i]);
        }
        if (j < end) {
            const bf16x8 p = *(const bf16x8*)(efb + (size_t)srt[j] * D + l * 8);
#pragma unroll
            for (int i = 0; i < 8; ++i) acc[i] += bf2f((unsigned short)p[i]);
        }
        const int deg = end - beg;
        const float inv = deg ? 1.f / (float)deg : 0.f;
        const bf16x8 r = *(const bf16x8*)(resb + (size_t)n * D + l * 8);
        const float4 rb0 = *(const float4*)(rb + l * 8);
        const float4 rb1 = *(const float4*)(rb + l * 8 + 4);
        const float4 cb0 = *(const float4*)(cb + l * 8);
        const float4 cb1 = *(const float4*)(cb + l * 8 + 4);
        float4 o0, o1;
        o0.x = bf2f((unsigned short)r[0]) + acc[0] * inv + rb0.x + cb0.x;
        o0.y = bf2f((unsigned short)r[1]) + acc[1] * inv + rb0.y + cb0.y;
        o0.z = bf2f((unsigned short)r[2]) + acc[2] * inv + rb0.z + cb0.z;
        o0.w = bf2f((unsigned short)r[3]) + acc[3] * inv + rb0.w + cb0.w;
        o1.x = bf2f((unsigned short)r[4]) + acc[4] * inv + rb1.x + cb1.x;
        o1.y = bf2f((unsigned short)r[5]) + acc[5] * inv + rb1.y + cb1.y;
        o1.z = bf2f((unsigned short)r[6]) + acc[6] * inv + rb1.z + cb1.z;
        o1.w = bf2f((unsigned short)r[7]) + acc[7] * inv + rb1.w + cb1.w;
        const size_t o = (size_t)n * D + l * 8;
        *(float4*)(out + o) = o0;
        *(float4*)(out + o + 4) = o1;
    }
}

// ---------------------------------------------------------------------------
extern "C" void kernel_launch(void* const* d_in, const int* in_sizes, int n_in,
                              void* d_out, int out_size, void* d_ws,
                              size_t ws_size, hipStream_t stream) {
    const float* x  = (const float*)d_in[0];
    const int* nidx = (const int*)d_in[1];
    const int* eidx = (const int*)d_in[2];
    const float* cW = (const float*)d_in[3];
    const float* cb = (const float*)d_in[4];
    const float* rW = (const float*)d_in[5];
    const float* rb = (const float*)d_in[6];
    float* out = (float*)d_out;

    char* ws = (char*)d_ws;
    size_t off = 0;
    auto alloc = [&](size_t bytes) {
        size_t o = off;
        off += (bytes + 255) & ~(size_t)255;
        return o;
    };
    unsigned short* yb   = (unsigned short*)(ws + alloc((size_t)N_NODES * D * 2));
    unsigned short* resb = (unsigned short*)(ws + alloc((size_t)N_NODES * D * 2));
    unsigned short* efb  = (unsigned short*)(ws + alloc((size_t)N_EDGES * D * 2));
    unsigned short* wtc  = (unsigned short*)(ws + alloc((size_t)D * D * 2));
    unsigned short* wtr  = (unsigned short*)(ws + alloc((size_t)D * D * 2));
    int* bucket_e = (int*)(ws + alloc((size_t)NBE * ECAP * 4));
    int* bucket_n = (int*)(ws + alloc((size_t)NBN * NCAP * 4));
    int* gcur     = (int*)(ws + alloc((size_t)(NBE + NBN) * 4));
    int* gcur_e = gcur;
    int* gcur_n = gcur + NBE;

    hipMemsetAsync(gcur, 0, (size_t)(NBE + NBN) * 4, stream);

    // bin_pass also produces wtc/wtr (gemm depends on them)
    bin_pass<<<NBLK_A + 8, 256, 0, stream>>>(nidx, eidx, cW, rW, wtc, wtr,
                                             bucket_e, bucket_n, gcur_e, gcur_n);

    mfma_gemm<<<(NTILES + 1) / 2, 512, 0, stream>>>(x, wtc, wtr, yb, resb);

    edge_aggregate<<<NBE, 256, 0, stream>>>(bucket_e, gcur_e, yb, efb);
    node_aggregate<<<NBN, 256, 0, stream>>>(bucket_n, gcur_n, efb, resb,
                                            rb, cb, out);
}